// Round 4
// baseline (940.688 us; speedup 1.0000x reference)
//
#include <hip/hip_runtime.h>
#include <hip/hip_bf16.h>
#include <math.h>

#define H 512
#define NT 6
#define BM 64
#define BN 64

typedef short bf16x8 __attribute__((ext_vector_type(8)));
typedef float f32x4 __attribute__((ext_vector_type(4)));

__device__ __forceinline__ float sigmoidf_(float x) { return 1.0f / (1.0f + expf(-x)); }

__device__ __forceinline__ unsigned short f2bf(float f) {
    unsigned int u = __float_as_uint(f);
    u = (u + 0x7FFF + ((u >> 16) & 1)) >> 16;
    return (unsigned short)u;
}
__device__ __forceinline__ float bf2f(unsigned short s) {
    unsigned int u = ((unsigned int)s) << 16;
    return __uint_as_float(u);
}

// async global->LDS, 16B per lane; LDS dest is wave-uniform base + lane*16
__device__ __forceinline__ void async16(const unsigned short* g, short* l) {
    __builtin_amdgcn_global_load_lds((const __attribute__((address_space(1))) void*)g,
                                     (__attribute__((address_space(3))) void*)l, 16, 0, 0);
}

// ---------------- type counting sort (block-aggregated) ----------------
__global__ void hist_kernel(const int* __restrict__ etype, int E, int* __restrict__ meta) {
    __shared__ int lh[NT];
    if (threadIdx.x < NT) lh[threadIdx.x] = 0;
    __syncthreads();
    int i = blockIdx.x * blockDim.x + threadIdx.x;
    if (i < E) atomicAdd(&lh[etype[i]], 1);
    __syncthreads();
    if (threadIdx.x < NT) {
        int c = lh[threadIdx.x];
        if (c) atomicAdd(&meta[threadIdx.x], c);
    }
}

__global__ void prefix_kernel(int* __restrict__ meta) {
    if (threadIdx.x == 0 && blockIdx.x == 0) {
        int acc = 0;
        for (int t = 0; t < NT; ++t) {
            meta[8 + t]  = acc;
            meta[16 + t] = acc;
            acc += ((meta[t] + BM - 1) / BM) * BM;
        }
        meta[8 + NT] = acc;
    }
}

__global__ void scatter_perm_kernel(const int* __restrict__ etype, int E,
                                    int* __restrict__ meta, int* __restrict__ perm) {
    __shared__ int lcount[NT];
    __shared__ int lbase[NT];
    const int tid = threadIdx.x;
    if (tid < NT) lcount[tid] = 0;
    __syncthreads();
    int i = blockIdx.x * blockDim.x + tid;
    int t = 0, rank = 0;
    if (i < E) {
        t = etype[i];
        rank = atomicAdd(&lcount[t], 1);
    }
    __syncthreads();
    if (tid < NT) {
        int c = lcount[tid];
        lbase[tid] = c ? atomicAdd(&meta[16 + tid], c) : 0;
    }
    __syncthreads();
    if (i < E) perm[lbase[t] + rank] = i;
}

// ---------------- dest counting sort: hist + scan(3) + slots ----------------
__global__ void node_hist_kernel(const int* __restrict__ dst, int E, int* __restrict__ cnt) {
    int i = blockIdx.x * blockDim.x + threadIdx.x;
    if (i < E) atomicAdd(&cnt[dst[i]], 1);
}

// scan1: per-block (1024 elems) exclusive scan -> nodeStart, block totals -> partials
__global__ void scan1_kernel(const int* __restrict__ cnt, int n,
                             int* __restrict__ nodeStart, int* __restrict__ partials) {
    __shared__ int sh[256];
    const int tid = threadIdx.x;
    const int base = blockIdx.x * 1024 + tid * 4;
    int v[4];
    int tsum = 0;
    #pragma unroll
    for (int j = 0; j < 4; ++j) { v[j] = (base + j < n) ? cnt[base + j] : 0; tsum += v[j]; }
    sh[tid] = tsum;
    __syncthreads();
    for (int ofs = 1; ofs < 256; ofs <<= 1) {
        int add = (tid >= ofs) ? sh[tid - ofs] : 0;
        __syncthreads();
        sh[tid] += add;
        __syncthreads();
    }
    int run = sh[tid] - tsum;
    #pragma unroll
    for (int j = 0; j < 4; ++j) {
        if (base + j < n) nodeStart[base + j] = run;
        run += v[j];
    }
    if (tid == 255) partials[blockIdx.x] = sh[255];
}

__global__ void scan2_kernel(int* __restrict__ partials, int nB, int* __restrict__ nodeStart, int n) {
    if (threadIdx.x == 0 && blockIdx.x == 0) {
        int acc = 0;
        for (int b = 0; b < nB; ++b) { int t = partials[b]; partials[b] = acc; acc += t; }
        nodeStart[n] = acc;
    }
}

__global__ void scan3_kernel(int* __restrict__ nodeStart, const int* __restrict__ partials, int n) {
    int i = blockIdx.x * blockDim.x + threadIdx.x;
    if (i < n) nodeStart[i] += partials[i >> 10];
}

__global__ void slot_kernel(const int* __restrict__ dst, int E, const int* __restrict__ nodeStart,
                            int* __restrict__ cursor, int* __restrict__ destSlot) {
    int i = blockIdx.x * blockDim.x + threadIdx.x;
    if (i < E) {
        int d = dst[i];
        destSlot[i] = nodeStart[d] + atomicAdd(&cursor[d], 1);
    }
}

// ---------------- converts ----------------
__global__ void conv_bf16_kernel(const float* __restrict__ in, unsigned short* __restrict__ out, int n4) {
    int i = blockIdx.x * blockDim.x + threadIdx.x;
    if (i < n4) {
        float4 v = ((const float4*)in)[i];
        ushort4 o;
        o.x = f2bf(v.x); o.y = f2bf(v.y); o.z = f2bf(v.z); o.w = f2bf(v.w);
        ((ushort4*)out)[i] = o;
    }
}

__global__ void conv_gru_w_kernel(const float* __restrict__ Wir, const float* __restrict__ Wiz,
                                  const float* __restrict__ Win, const float* __restrict__ Whr,
                                  const float* __restrict__ Whz, const float* __restrict__ Whn,
                                  unsigned short* __restrict__ Brt, unsigned short* __restrict__ Bzt,
                                  unsigned short* __restrict__ Bnit, unsigned short* __restrict__ Bnht) {
    int idx = blockIdx.x * blockDim.x + threadIdx.x;
    if (idx >= 512 * 1024) return;
    int n = idx >> 10;
    int k = idx & 1023;
    int kk = k & 511;
    const float* wr = (k < 512) ? Wir : Whr;
    const float* wz = (k < 512) ? Wiz : Whz;
    Brt[idx] = f2bf(wr[kk * H + n]);
    Bzt[idx] = f2bf(wz[kk * H + n]);
    if (k < 512) Bnit[n * H + k]  = f2bf(Win[k * H + n]);
    else         Bnht[n * H + kk] = f2bf(Whn[kk * H + n]);
}

__global__ void conv_edge_w_kernel(const float* __restrict__ W_edge, unsigned short* __restrict__ WeT) {
    int idx = blockIdx.x * blockDim.x + threadIdx.x;
    if (idx >= 3072 * 512) return;
    int n = idx >> 9;
    int k = idx & 511;
    WeT[idx] = f2bf(W_edge[(size_t)k * (NT * H) + n]);
}

// ---------------- edge message GEMM (m97-style) -> bf16 msgs at dest-slots ----------------
__global__ __launch_bounds__(256)
void edge_msg_mfma2(const unsigned short* __restrict__ emb_bf,
                    const int* __restrict__ src_idx,
                    const float* __restrict__ b_edge,
                    const unsigned short* __restrict__ WeT,
                    const int* __restrict__ meta,
                    const int* __restrict__ perm,
                    const int* __restrict__ destSlot,
                    unsigned short* __restrict__ msgbuf)
{
    // 8 fragment-groups of 512 shorts: A groups 0-3, B groups 4-7
    __shared__ __align__(16) short lds[8 * 512];
    __shared__ __align__(16) short Cs[64][72];
    __shared__ int ls_slot[BM];
    __shared__ int ls_srcb[BM];

    const int rowBase = blockIdx.y * BM;
    if (rowBase >= meta[8 + NT]) return;
    int t = 0;
    while (rowBase >= meta[8 + t + 1]) ++t;

    const int colBase = blockIdx.x * BN;
    const int tid = threadIdx.x;
    if (tid < BM) {
        int e = perm[rowBase + tid];
        ls_slot[tid] = (e >= 0) ? destSlot[e] : -1;
        ls_srcb[tid] = (e >= 0) ? src_idx[e] * H : 0;
    }
    __syncthreads();

    const int lane = tid & 63;
    const int wv = tid >> 6;
    const int r = lane & 15;
    const int q = lane >> 4;
    const int wm = (wv >> 1) * 32;
    const int wn = (wv & 1) * 32;

    // staging: wave wv stages combined groups 2wv, 2wv+1
    const unsigned short* pg[2];
    #pragma unroll
    for (int s = 0; s < 2; ++s) {
        int grp = wv * 2 + s;
        if (grp < 4) pg[s] = emb_bf + (size_t)ls_srcb[grp * 16 + r] + q * 8;
        else         pg[s] = WeT + ((size_t)(t * H + colBase + (grp - 4) * 16 + r)) * H + q * 8;
    }
    short* ld0 = &lds[(wv * 2) * 512];
    short* ld1 = &lds[(wv * 2 + 1) * 512];

    f32x4 acc[2][2];
    #pragma unroll
    for (int i = 0; i < 2; ++i)
        #pragma unroll
        for (int j = 0; j < 2; ++j) acc[i][j] = (f32x4){0.f, 0.f, 0.f, 0.f};

    for (int ks = 0; ks < 16; ++ks) {
        async16(pg[0], ld0);
        async16(pg[1], ld1);
        pg[0] += 32; pg[1] += 32;
        __syncthreads();
        bf16x8 a0 = *(const bf16x8*)&lds[(wm / 16 + 0) * 512 + lane * 8];
        bf16x8 a1 = *(const bf16x8*)&lds[(wm / 16 + 1) * 512 + lane * 8];
        bf16x8 b0 = *(const bf16x8*)&lds[(4 + wn / 16 + 0) * 512 + lane * 8];
        bf16x8 b1 = *(const bf16x8*)&lds[(4 + wn / 16 + 1) * 512 + lane * 8];
        acc[0][0] = __builtin_amdgcn_mfma_f32_16x16x32_bf16(a0, b0, acc[0][0], 0, 0, 0);
        acc[0][1] = __builtin_amdgcn_mfma_f32_16x16x32_bf16(a0, b1, acc[0][1], 0, 0, 0);
        acc[1][0] = __builtin_amdgcn_mfma_f32_16x16x32_bf16(a1, b0, acc[1][0], 0, 0, 0);
        acc[1][1] = __builtin_amdgcn_mfma_f32_16x16x32_bf16(a1, b1, acc[1][1], 0, 0, 0);
        __syncthreads();
    }

    // epilogue: add bias, round to bf16, transpose through LDS, coalesced scatter
    float bias0 = b_edge[t * H + colBase + wn + r];
    float bias1 = b_edge[t * H + colBase + wn + 16 + r];
    #pragma unroll
    for (int i = 0; i < 2; ++i)
        #pragma unroll
        for (int reg = 0; reg < 4; ++reg) {
            int row = wm + i * 16 + q * 4 + reg;
            Cs[row][wn + r]      = (short)f2bf(acc[i][0][reg] + bias0);
            Cs[row][wn + 16 + r] = (short)f2bf(acc[i][1][reg] + bias1);
        }
    __syncthreads();

    int row = tid >> 2;
    int cc = (tid & 3) * 16;
    int slot = ls_slot[row];
    if (slot >= 0) {
        uint4* dst0 = (uint4*)&msgbuf[(size_t)slot * H + colBase + cc];
        dst0[0] = *(const uint4*)&Cs[row][cc];
        dst0[1] = *(const uint4*)&Cs[row][cc + 8];
    }
}

// ---------------- segment reduce (dest-sorted msgs) -> prop_bf ----------------
__global__ void segreduce_kernel(const unsigned short* __restrict__ msgbuf,
                                 const int* __restrict__ nodeStart,
                                 unsigned short* __restrict__ prop_bf, int N) {
    int idx = blockIdx.x * blockDim.x + threadIdx.x;
    if (idx >= N * 64) return;
    int node = idx >> 6;
    int cg = (idx & 63) * 8;
    int s0 = nodeStart[node], s1 = nodeStart[node + 1];
    float acc[8] = {0.f, 0.f, 0.f, 0.f, 0.f, 0.f, 0.f, 0.f};
    for (int s = s0; s < s1; ++s) {
        uint4 v = *(const uint4*)&msgbuf[(size_t)s * H + cg];
        const unsigned short* u = (const unsigned short*)&v;
        #pragma unroll
        for (int j = 0; j < 8; ++j) acc[j] += bf2f(u[j]);
    }
    unsigned short o[8];
    #pragma unroll
    for (int j = 0; j < 8; ++j) o[j] = f2bf(acc[j]);
    *(uint4*)&prop_bf[(size_t)node * H + cg] = *(const uint4*)o;
}

// ---------------- fused GRU (m97-style): A' = [P | H] over K=1024 ----------------
__global__ __launch_bounds__(256)
void gru_mfma2(const unsigned short* __restrict__ prop_bf,
               const unsigned short* __restrict__ emb_bf,
               const float* __restrict__ emb_f32,
               const unsigned short* __restrict__ Brt,
               const unsigned short* __restrict__ Bzt,
               const unsigned short* __restrict__ Bnit,
               const unsigned short* __restrict__ Bnht,
               const float* __restrict__ bir, const float* __restrict__ biz,
               const float* __restrict__ bin, const float* __restrict__ bhn,
               float* __restrict__ out, int N)
{
    // 4 tiles (A, Br, Bz, Bn) x 4 groups x 512 shorts
    __shared__ __align__(16) short lds[4 * 2048];

    const int tid = threadIdx.x;
    const int lane = tid & 63;
    const int wv = tid >> 6;
    const int r = lane & 15;
    const int q = lane >> 4;
    const int rowBase = blockIdx.y * BM;
    const int colBase = blockIdx.x * BN;
    const int wm = (wv >> 1) * 32;
    const int wn = (wv & 1) * 32;

    f32x4 accR[2][2], accZ[2][2], accNI[2][2], accNH[2][2];
    #pragma unroll
    for (int i = 0; i < 2; ++i)
        #pragma unroll
        for (int j = 0; j < 2; ++j) {
            accR[i][j] = (f32x4){0.f, 0.f, 0.f, 0.f};
            accZ[i][j] = accR[i][j];
            accNI[i][j] = accR[i][j];
            accNH[i][j] = accR[i][j];
        }

    short* ldsT = &lds[wv * 2048];

    for (int half = 0; half < 2; ++half) {
        // per-wave staging pointers for its tile's 4 groups
        const unsigned short* pg[4];
        if (wv == 0) {
            const unsigned short* s = half ? emb_bf : prop_bf;
            #pragma unroll
            for (int g = 0; g < 4; ++g)
                pg[g] = s + (size_t)(rowBase + g * 16 + r) * H + q * 8;
        } else if (wv == 1) {
            #pragma unroll
            for (int g = 0; g < 4; ++g)
                pg[g] = Brt + (size_t)(colBase + g * 16 + r) * 1024 + half * 512 + q * 8;
        } else if (wv == 2) {
            #pragma unroll
            for (int g = 0; g < 4; ++g)
                pg[g] = Bzt + (size_t)(colBase + g * 16 + r) * 1024 + half * 512 + q * 8;
        } else {
            const unsigned short* s = half ? Bnht : Bnit;
            #pragma unroll
            for (int g = 0; g < 4; ++g)
                pg[g] = s + (size_t)(colBase + g * 16 + r) * H + q * 8;
        }

        f32x4 (&accN)[2][2] = half ? accNH : accNI;

        for (int ks = 0; ks < 16; ++ks) {
            #pragma unroll
            for (int g = 0; g < 4; ++g) {
                async16(pg[g], ldsT + g * 512);
                pg[g] += 32;
            }
            __syncthreads();

            bf16x8 a0 = *(const bf16x8*)&lds[0 * 2048 + (wm / 16 + 0) * 512 + lane * 8];
            bf16x8 a1 = *(const bf16x8*)&lds[0 * 2048 + (wm / 16 + 1) * 512 + lane * 8];
            bf16x8 br0 = *(const bf16x8*)&lds[1 * 2048 + (wn / 16 + 0) * 512 + lane * 8];
            bf16x8 br1 = *(const bf16x8*)&lds[1 * 2048 + (wn / 16 + 1) * 512 + lane * 8];
            bf16x8 bz0 = *(const bf16x8*)&lds[2 * 2048 + (wn / 16 + 0) * 512 + lane * 8];
            bf16x8 bz1 = *(const bf16x8*)&lds[2 * 2048 + (wn / 16 + 1) * 512 + lane * 8];
            bf16x8 bn0 = *(const bf16x8*)&lds[3 * 2048 + (wn / 16 + 0) * 512 + lane * 8];
            bf16x8 bn1 = *(const bf16x8*)&lds[3 * 2048 + (wn / 16 + 1) * 512 + lane * 8];

            accR[0][0] = __builtin_amdgcn_mfma_f32_16x16x32_bf16(a0, br0, accR[0][0], 0, 0, 0);
            accR[0][1] = __builtin_amdgcn_mfma_f32_16x16x32_bf16(a0, br1, accR[0][1], 0, 0, 0);
            accR[1][0] = __builtin_amdgcn_mfma_f32_16x16x32_bf16(a1, br0, accR[1][0], 0, 0, 0);
            accR[1][1] = __builtin_amdgcn_mfma_f32_16x16x32_bf16(a1, br1, accR[1][1], 0, 0, 0);
            accZ[0][0] = __builtin_amdgcn_mfma_f32_16x16x32_bf16(a0, bz0, accZ[0][0], 0, 0, 0);
            accZ[0][1] = __builtin_amdgcn_mfma_f32_16x16x32_bf16(a0, bz1, accZ[0][1], 0, 0, 0);
            accZ[1][0] = __builtin_amdgcn_mfma_f32_16x16x32_bf16(a1, bz0, accZ[1][0], 0, 0, 0);
            accZ[1][1] = __builtin_amdgcn_mfma_f32_16x16x32_bf16(a1, bz1, accZ[1][1], 0, 0, 0);
            accN[0][0] = __builtin_amdgcn_mfma_f32_16x16x32_bf16(a0, bn0, accN[0][0], 0, 0, 0);
            accN[0][1] = __builtin_amdgcn_mfma_f32_16x16x32_bf16(a0, bn1, accN[0][1], 0, 0, 0);
            accN[1][0] = __builtin_amdgcn_mfma_f32_16x16x32_bf16(a1, bn0, accN[1][0], 0, 0, 0);
            accN[1][1] = __builtin_amdgcn_mfma_f32_16x16x32_bf16(a1, bn1, accN[1][1], 0, 0, 0);
            __syncthreads();
        }
    }

    #pragma unroll
    for (int i = 0; i < 2; ++i) {
        #pragma unroll
        for (int reg = 0; reg < 4; ++reg) {
            int row = rowBase + wm + i * 16 + q * 4 + reg;
            if (row >= N) continue;
            #pragma unroll
            for (int j = 0; j < 2; ++j) {
                int col = colBase + wn + j * 16 + r;
                float rg = sigmoidf_(accR[i][j][reg] + bir[col]);
                float zg = sigmoidf_(accZ[i][j][reg] + biz[col]);
                float ng = tanhf(accNI[i][j][reg] + bin[col] + rg * (accNH[i][j][reg] + bhn[col]));
                float h = emb_f32[(size_t)row * H + col];
                out[(size_t)row * H + col] = (1.0f - zg) * ng + zg * h;
            }
        }
    }
}

extern "C" void kernel_launch(void* const* d_in, const int* in_sizes, int n_in,
                              void* d_out, int out_size, void* d_ws, size_t ws_size,
                              hipStream_t stream) {
    const float* emb     = (const float*)d_in[0];
    const int*   src_idx = (const int*)d_in[1];
    const int*   dst_idx = (const int*)d_in[2];
    const int*   etype   = (const int*)d_in[3];
    const float* W_edge  = (const float*)d_in[6];
    const float* b_edge  = (const float*)d_in[7];
    const float* Wir = (const float*)d_in[8];
    const float* Wiz = (const float*)d_in[9];
    const float* Win = (const float*)d_in[10];
    const float* bir = (const float*)d_in[11];
    const float* biz = (const float*)d_in[12];
    const float* bin = (const float*)d_in[13];
    const float* Whr = (const float*)d_in[14];
    const float* Whz = (const float*)d_in[15];
    const float* Whn = (const float*)d_in[16];
    const float* bhn = (const float*)d_in[17];

    const int E = in_sizes[1];
    const int N = in_sizes[0] / H;
    const int NH = N * H;
    const int maxRowTiles = (E + BM - 1) / BM + NT;

    char* ws = (char*)d_ws;
    unsigned short* prop_bf  = (unsigned short*)ws;  ws += (size_t)NH * 2;
    unsigned short* emb_bf   = (unsigned short*)ws;  ws += (size_t)NH * 2;
    unsigned short* msgbuf   = (unsigned short*)ws;  ws += (size_t)E * H * 2;
    unsigned short* Brt      = (unsigned short*)ws;  ws += 512 * 1024 * 2;
    unsigned short* Bzt      = (unsigned short*)ws;  ws += 512 * 1024 * 2;
    unsigned short* Bnit     = (unsigned short*)ws;  ws += 512 * 512 * 2;
    unsigned short* Bnht     = (unsigned short*)ws;  ws += 512 * 512 * 2;
    unsigned short* WeT      = (unsigned short*)ws;  ws += 3072 * 512 * 2;
    int* meta      = (int*)ws;  ws += 32 * 4;
    int* typePerm  = (int*)ws;  ws += (size_t)maxRowTiles * BM * 4;
    int* nodeCnt   = (int*)ws;  ws += (size_t)N * 4;
    int* nodeStart = (int*)ws;  ws += ((size_t)N + 4) * 4;
    int* cursor    = (int*)ws;  ws += (size_t)N * 4;
    int* partials  = (int*)ws;  ws += 64 * 4;
    int* destSlot  = (int*)ws;

    hipMemsetAsync(meta, 0, 32 * 4, stream);
    hipMemsetAsync(typePerm, 0xFF, (size_t)maxRowTiles * BM * 4, stream);
    hipMemsetAsync(nodeCnt, 0, (size_t)N * 4, stream);
    hipMemsetAsync(cursor, 0, (size_t)N * 4, stream);

    const int n4 = NH / 4;
    conv_bf16_kernel<<<(n4 + 255) / 256, 256, 0, stream>>>(emb, emb_bf, n4);
    conv_gru_w_kernel<<<(512 * 1024 + 255) / 256, 256, 0, stream>>>(
        Wir, Wiz, Win, Whr, Whz, Whn, Brt, Bzt, Bnit, Bnht);
    conv_edge_w_kernel<<<(3072 * 512 + 255) / 256, 256, 0, stream>>>(W_edge, WeT);

    // type sort
    hist_kernel<<<(E + 255) / 256, 256, 0, stream>>>(etype, E, meta);
    prefix_kernel<<<1, 64, 0, stream>>>(meta);
    scatter_perm_kernel<<<(E + 255) / 256, 256, 0, stream>>>(etype, E, meta, typePerm);

    // dest sort (slots)
    node_hist_kernel<<<(E + 255) / 256, 256, 0, stream>>>(dst_idx, E, nodeCnt);
    const int nB = (N + 1023) / 1024;
    scan1_kernel<<<nB, 256, 0, stream>>>(nodeCnt, N, nodeStart, partials);
    scan2_kernel<<<1, 64, 0, stream>>>(partials, nB, nodeStart, N);
    scan3_kernel<<<(N + 255) / 256, 256, 0, stream>>>(nodeStart, partials, N);
    slot_kernel<<<(E + 255) / 256, 256, 0, stream>>>(dst_idx, E, nodeStart, cursor, destSlot);

    // edge messages -> dest-sorted bf16 msgbuf
    dim3 egrid(H / BN, maxRowTiles);
    edge_msg_mfma2<<<egrid, 256, 0, stream>>>(emb_bf, src_idx, b_edge, WeT,
                                              meta, typePerm, destSlot, msgbuf);

    // segment reduce -> prop_bf (writes every element; no memset needed)
    segreduce_kernel<<<((size_t)N * 64 + 255) / 256, 256, 0, stream>>>(msgbuf, nodeStart, prop_bf, N);

    // fused GRU
    dim3 ggrid(H / BN, (N + BM - 1) / BM);
    gru_mfma2<<<ggrid, 256, 0, stream>>>(prop_bf, emb_bf, emb, Brt, Bzt, Bnit, Bnht,
                                         bir, biz, bin, bhn, (float*)d_out, N);
}

// Round 5
// 931.759 us; speedup vs baseline: 1.0096x; 1.0096x over previous
//
#include <hip/hip_runtime.h>
#include <hip/hip_bf16.h>
#include <math.h>

#define H 512
#define NT 6
#define BM 64
#define BN 64

typedef short bf16x8 __attribute__((ext_vector_type(8)));
typedef float f32x4 __attribute__((ext_vector_type(4)));

__device__ __forceinline__ float sigmoidf_(float x) { return 1.0f / (1.0f + expf(-x)); }

__device__ __forceinline__ unsigned short f2bf(float f) {
    unsigned int u = __float_as_uint(f);
    u = (u + 0x7FFF + ((u >> 16) & 1)) >> 16;
    return (unsigned short)u;
}
__device__ __forceinline__ float bf2f(unsigned short s) {
    unsigned int u = ((unsigned int)s) << 16;
    return __uint_as_float(u);
}

// async global->LDS, 16B per lane; LDS dest is wave-uniform base + lane*16
__device__ __forceinline__ void async16(const unsigned short* g, short* l) {
    __builtin_amdgcn_global_load_lds((const __attribute__((address_space(1))) void*)g,
                                     (__attribute__((address_space(3))) void*)l, 16, 0, 0);
}

// ---------------- type counting sort (block-aggregated) ----------------
__global__ void hist_kernel(const int* __restrict__ etype, int E, int* __restrict__ meta) {
    __shared__ int lh[NT];
    if (threadIdx.x < NT) lh[threadIdx.x] = 0;
    __syncthreads();
    int i = blockIdx.x * blockDim.x + threadIdx.x;
    if (i < E) atomicAdd(&lh[etype[i]], 1);
    __syncthreads();
    if (threadIdx.x < NT) {
        int c = lh[threadIdx.x];
        if (c) atomicAdd(&meta[threadIdx.x], c);
    }
}

__global__ void prefix_kernel(int* __restrict__ meta) {
    if (threadIdx.x == 0 && blockIdx.x == 0) {
        int acc = 0;
        for (int t = 0; t < NT; ++t) {
            meta[8 + t]  = acc;
            meta[16 + t] = acc;
            acc += ((meta[t] + BM - 1) / BM) * BM;
        }
        meta[8 + NT] = acc;
    }
}

__global__ void scatter_perm_kernel(const int* __restrict__ etype, int E,
                                    int* __restrict__ meta, int* __restrict__ perm) {
    __shared__ int lcount[NT];
    __shared__ int lbase[NT];
    const int tid = threadIdx.x;
    if (tid < NT) lcount[tid] = 0;
    __syncthreads();
    int i = blockIdx.x * blockDim.x + tid;
    int t = 0, rank = 0;
    if (i < E) {
        t = etype[i];
        rank = atomicAdd(&lcount[t], 1);
    }
    __syncthreads();
    if (tid < NT) {
        int c = lcount[tid];
        lbase[tid] = c ? atomicAdd(&meta[16 + tid], c) : 0;
    }
    __syncthreads();
    if (i < E) perm[lbase[t] + rank] = i;
}

// ---------------- dest counting sort: hist + scan(3) + slots ----------------
__global__ void node_hist_kernel(const int* __restrict__ dst, int E, int* __restrict__ cnt) {
    int i = blockIdx.x * blockDim.x + threadIdx.x;
    if (i < E) atomicAdd(&cnt[dst[i]], 1);
}

__global__ void scan1_kernel(const int* __restrict__ cnt, int n,
                             int* __restrict__ nodeStart, int* __restrict__ partials) {
    __shared__ int sh[256];
    const int tid = threadIdx.x;
    const int base = blockIdx.x * 1024 + tid * 4;
    int v[4];
    int tsum = 0;
    #pragma unroll
    for (int j = 0; j < 4; ++j) { v[j] = (base + j < n) ? cnt[base + j] : 0; tsum += v[j]; }
    sh[tid] = tsum;
    __syncthreads();
    for (int ofs = 1; ofs < 256; ofs <<= 1) {
        int add = (tid >= ofs) ? sh[tid - ofs] : 0;
        __syncthreads();
        sh[tid] += add;
        __syncthreads();
    }
    int run = sh[tid] - tsum;
    #pragma unroll
    for (int j = 0; j < 4; ++j) {
        if (base + j < n) nodeStart[base + j] = run;
        run += v[j];
    }
    if (tid == 255) partials[blockIdx.x] = sh[255];
}

__global__ void scan2_kernel(int* __restrict__ partials, int nB, int* __restrict__ nodeStart, int n) {
    if (threadIdx.x == 0 && blockIdx.x == 0) {
        int acc = 0;
        for (int b = 0; b < nB; ++b) { int t = partials[b]; partials[b] = acc; acc += t; }
        nodeStart[n] = acc;
    }
}

__global__ void scan3_kernel(int* __restrict__ nodeStart, const int* __restrict__ partials, int n) {
    int i = blockIdx.x * blockDim.x + threadIdx.x;
    if (i < n) nodeStart[i] += partials[i >> 10];
}

__global__ void slot_kernel(const int* __restrict__ dst, int E, const int* __restrict__ nodeStart,
                            int* __restrict__ cursor, int* __restrict__ destSlot) {
    int i = blockIdx.x * blockDim.x + threadIdx.x;
    if (i < E) {
        int d = dst[i];
        destSlot[i] = nodeStart[d] + atomicAdd(&cursor[d], 1);
    }
}

// ---------------- converts ----------------
__global__ void conv_bf16_kernel(const float* __restrict__ in, unsigned short* __restrict__ out, int n4) {
    int i = blockIdx.x * blockDim.x + threadIdx.x;
    if (i < n4) {
        float4 v = ((const float4*)in)[i];
        ushort4 o;
        o.x = f2bf(v.x); o.y = f2bf(v.y); o.z = f2bf(v.z); o.w = f2bf(v.w);
        ((ushort4*)out)[i] = o;
    }
}

__global__ void conv_gru_w_kernel(const float* __restrict__ Wir, const float* __restrict__ Wiz,
                                  const float* __restrict__ Win, const float* __restrict__ Whr,
                                  const float* __restrict__ Whz, const float* __restrict__ Whn,
                                  unsigned short* __restrict__ Brt, unsigned short* __restrict__ Bzt,
                                  unsigned short* __restrict__ Bnit, unsigned short* __restrict__ Bnht) {
    int idx = blockIdx.x * blockDim.x + threadIdx.x;
    if (idx >= 512 * 1024) return;
    int n = idx >> 10;
    int k = idx & 1023;
    int kk = k & 511;
    const float* wr = (k < 512) ? Wir : Whr;
    const float* wz = (k < 512) ? Wiz : Whz;
    Brt[idx] = f2bf(wr[kk * H + n]);
    Bzt[idx] = f2bf(wz[kk * H + n]);
    if (k < 512) Bnit[n * H + k]  = f2bf(Win[k * H + n]);
    else         Bnht[n * H + kk] = f2bf(Whn[kk * H + n]);
}

__global__ void conv_edge_w_kernel(const float* __restrict__ W_edge, unsigned short* __restrict__ WeT) {
    int idx = blockIdx.x * blockDim.x + threadIdx.x;
    if (idx >= 3072 * 512) return;
    int n = idx >> 9;
    int k = idx & 511;
    WeT[idx] = f2bf(W_edge[(size_t)k * (NT * H) + n]);
}

// ---------------- edge message GEMM (2-stage pipelined) -> bf16 msgs at dest-slots ----------------
__global__ __launch_bounds__(256)
void edge_msg_mfma3(const unsigned short* __restrict__ emb_bf,
                    const int* __restrict__ src_idx,
                    const float* __restrict__ b_edge,
                    const unsigned short* __restrict__ WeT,
                    const int* __restrict__ meta,
                    const int* __restrict__ perm,
                    const int* __restrict__ destSlot,
                    unsigned short* __restrict__ msgbuf)
{
    // two buffers x 8 fragment-groups x 512 shorts
    __shared__ __align__(16) short lds[2][8 * 512];
    __shared__ __align__(16) short Cs[64][72];
    __shared__ int ls_slot[BM];
    __shared__ int ls_srcb[BM];

    const int rowBase = blockIdx.y * BM;
    if (rowBase >= meta[8 + NT]) return;
    int t = 0;
    while (rowBase >= meta[8 + t + 1]) ++t;

    const int colBase = blockIdx.x * BN;
    const int tid = threadIdx.x;
    if (tid < BM) {
        int e = perm[rowBase + tid];
        ls_slot[tid] = (e >= 0) ? destSlot[e] : -1;
        ls_srcb[tid] = (e >= 0) ? src_idx[e] * H : 0;
    }
    __syncthreads();

    const int lane = tid & 63;
    const int wv = tid >> 6;
    const int r = lane & 15;
    const int q = lane >> 4;
    const int wm = (wv >> 1) * 32;
    const int wn = (wv & 1) * 32;

    // staging: wave wv stages groups 2wv, 2wv+1 (A groups 0-3, B groups 4-7)
    const unsigned short* pg[2];
    #pragma unroll
    for (int s = 0; s < 2; ++s) {
        int grp = wv * 2 + s;
        if (grp < 4) pg[s] = emb_bf + (size_t)ls_srcb[grp * 16 + r] + q * 8;
        else         pg[s] = WeT + ((size_t)(t * H + colBase + (grp - 4) * 16 + r)) * H + q * 8;
    }
    short* my0 = &lds[0][(wv * 2) * 512];
    short* my1 = &lds[0][(wv * 2 + 1) * 512];

    f32x4 acc[2][2];
    #pragma unroll
    for (int i = 0; i < 2; ++i)
        #pragma unroll
        for (int j = 0; j < 2; ++j) acc[i][j] = (f32x4){0.f, 0.f, 0.f, 0.f};

    // prologue: stage step 0 into buf0
    async16(pg[0], my0);
    async16(pg[1], my1);

    for (int ks = 0; ks < 16; ++ks) {
        __syncthreads();                    // drains step-ks loads (issued last iter)
        if (ks < 15) {                      // issue step ks+1 into other buffer
            const int off = (ks + 1) * 32;
            const int bofs = ((ks & 1) ? 0 : 4096);
            async16(pg[0] + off, my0 + bofs);
            async16(pg[1] + off, my1 + bofs);
        }
        const short* L = &lds[ks & 1][0];
        bf16x8 a0 = *(const bf16x8*)&L[(wm / 16 + 0) * 512 + lane * 8];
        bf16x8 a1 = *(const bf16x8*)&L[(wm / 16 + 1) * 512 + lane * 8];
        bf16x8 b0 = *(const bf16x8*)&L[(4 + wn / 16 + 0) * 512 + lane * 8];
        bf16x8 b1 = *(const bf16x8*)&L[(4 + wn / 16 + 1) * 512 + lane * 8];
        acc[0][0] = __builtin_amdgcn_mfma_f32_16x16x32_bf16(a0, b0, acc[0][0], 0, 0, 0);
        acc[0][1] = __builtin_amdgcn_mfma_f32_16x16x32_bf16(a0, b1, acc[0][1], 0, 0, 0);
        acc[1][0] = __builtin_amdgcn_mfma_f32_16x16x32_bf16(a1, b0, acc[1][0], 0, 0, 0);
        acc[1][1] = __builtin_amdgcn_mfma_f32_16x16x32_bf16(a1, b1, acc[1][1], 0, 0, 0);
    }
    __syncthreads();

    // epilogue: add bias, round to bf16, transpose through LDS, coalesced scatter
    float bias0 = b_edge[t * H + colBase + wn + r];
    float bias1 = b_edge[t * H + colBase + wn + 16 + r];
    #pragma unroll
    for (int i = 0; i < 2; ++i)
        #pragma unroll
        for (int reg = 0; reg < 4; ++reg) {
            int row = wm + i * 16 + q * 4 + reg;
            Cs[row][wn + r]      = (short)f2bf(acc[i][0][reg] + bias0);
            Cs[row][wn + 16 + r] = (short)f2bf(acc[i][1][reg] + bias1);
        }
    __syncthreads();

    int row = tid >> 2;
    int cc = (tid & 3) * 16;
    int slot = ls_slot[row];
    if (slot >= 0) {
        uint4* dst0 = (uint4*)&msgbuf[(size_t)slot * H + colBase + cc];
        dst0[0] = *(const uint4*)&Cs[row][cc];
        dst0[1] = *(const uint4*)&Cs[row][cc + 8];
    }
}

// ---------------- segment reduce (dest-sorted msgs) -> prop_bf ----------------
__global__ void segreduce_kernel(const unsigned short* __restrict__ msgbuf,
                                 const int* __restrict__ nodeStart,
                                 unsigned short* __restrict__ prop_bf, int N) {
    int idx = blockIdx.x * blockDim.x + threadIdx.x;
    if (idx >= N * 64) return;
    int node = idx >> 6;
    int cg = (idx & 63) * 8;
    int s0 = nodeStart[node], s1 = nodeStart[node + 1];
    float acc[8] = {0.f, 0.f, 0.f, 0.f, 0.f, 0.f, 0.f, 0.f};
    for (int s = s0; s < s1; ++s) {
        uint4 v = *(const uint4*)&msgbuf[(size_t)s * H + cg];
        const unsigned short* u = (const unsigned short*)&v;
        #pragma unroll
        for (int j = 0; j < 8; ++j) acc[j] += bf2f(u[j]);
    }
    unsigned short o[8];
    #pragma unroll
    for (int j = 0; j < 8; ++j) o[j] = f2bf(acc[j]);
    *(uint4*)&prop_bf[(size_t)node * H + cg] = *(const uint4*)o;
}

// ---------------- fused GRU (2-stage pipelined): A' = [P | H] over K=1024 ----------------
__global__ __launch_bounds__(256)
void gru_mfma3(const unsigned short* __restrict__ prop_bf,
               const unsigned short* __restrict__ emb_bf,
               const float* __restrict__ emb_f32,
               const unsigned short* __restrict__ Brt,
               const unsigned short* __restrict__ Bzt,
               const unsigned short* __restrict__ Bnit,
               const unsigned short* __restrict__ Bnht,
               const float* __restrict__ bir, const float* __restrict__ biz,
               const float* __restrict__ bin, const float* __restrict__ bhn,
               float* __restrict__ out, int N)
{
    // two buffers x 4 tiles (A, Br, Bz, Bn) x 2048 shorts
    __shared__ __align__(16) short lds[2][4 * 2048];

    const int tid = threadIdx.x;
    const int lane = tid & 63;
    const int wv = tid >> 6;
    const int r = lane & 15;
    const int q = lane >> 4;
    const int rowBase = blockIdx.y * BM;
    const int colBase = blockIdx.x * BN;
    const int wm = (wv >> 1) * 32;
    const int wn = (wv & 1) * 32;

    // per-wave staging base pointers for half0 (h0) and half1 (h1), 4 groups each
    const unsigned short* h0[4];
    const unsigned short* h1[4];
    if (wv == 0) {
        #pragma unroll
        for (int g = 0; g < 4; ++g) {
            size_t rowoff = (size_t)(rowBase + g * 16 + r) * H + q * 8;
            h0[g] = prop_bf + rowoff;
            h1[g] = emb_bf + rowoff;
        }
    } else if (wv == 1) {
        #pragma unroll
        for (int g = 0; g < 4; ++g) {
            h0[g] = Brt + (size_t)(colBase + g * 16 + r) * 1024 + q * 8;
            h1[g] = h0[g] + 512;
        }
    } else if (wv == 2) {
        #pragma unroll
        for (int g = 0; g < 4; ++g) {
            h0[g] = Bzt + (size_t)(colBase + g * 16 + r) * 1024 + q * 8;
            h1[g] = h0[g] + 512;
        }
    } else {
        #pragma unroll
        for (int g = 0; g < 4; ++g) {
            size_t coloff = (size_t)(colBase + g * 16 + r) * H + q * 8;
            h0[g] = Bnit + coloff;
            h1[g] = Bnht + coloff;
        }
    }

    short* myl = &lds[0][wv * 2048];   // wave's tile region in buf0; buf1 at +8192 shorts

    f32x4 accR[2][2], accZ[2][2], accNI[2][2], accNH[2][2];
    #pragma unroll
    for (int i = 0; i < 2; ++i)
        #pragma unroll
        for (int j = 0; j < 2; ++j) {
            accR[i][j] = (f32x4){0.f, 0.f, 0.f, 0.f};
            accZ[i][j] = accR[i][j];
            accNI[i][j] = accR[i][j];
            accNH[i][j] = accR[i][j];
        }

    // prologue: stage step 0 into buf0
    #pragma unroll
    for (int g = 0; g < 4; ++g) async16(h0[g], myl + g * 512);

    #pragma unroll
    for (int half = 0; half < 2; ++half) {
        for (int ks = 0; ks < 16; ++ks) {
            __syncthreads();               // drains loads for this step (issued last iter)
            // issue next step into the other buffer
            {
                short* dst = myl + ((ks & 1) ? 0 : 8192);   // parity of (s+1)
                if (half == 0) {
                    if (ks < 15) {
                        const int off = (ks + 1) * 32;
                        #pragma unroll
                        for (int g = 0; g < 4; ++g) async16(h0[g] + off, dst + g * 512);
                    } else {
                        #pragma unroll
                        for (int g = 0; g < 4; ++g) async16(h1[g], dst + g * 512);
                    }
                } else if (ks < 15) {
                    const int off = (ks + 1) * 32;
                    #pragma unroll
                    for (int g = 0; g < 4; ++g) async16(h1[g] + off, dst + g * 512);
                }
            }

            const short* L = &lds[ks & 1][0];
            bf16x8 a0  = *(const bf16x8*)&L[0 * 2048 + (wm / 16 + 0) * 512 + lane * 8];
            bf16x8 a1  = *(const bf16x8*)&L[0 * 2048 + (wm / 16 + 1) * 512 + lane * 8];
            bf16x8 br0 = *(const bf16x8*)&L[1 * 2048 + (wn / 16 + 0) * 512 + lane * 8];
            bf16x8 br1 = *(const bf16x8*)&L[1 * 2048 + (wn / 16 + 1) * 512 + lane * 8];
            bf16x8 bz0 = *(const bf16x8*)&L[2 * 2048 + (wn / 16 + 0) * 512 + lane * 8];
            bf16x8 bz1 = *(const bf16x8*)&L[2 * 2048 + (wn / 16 + 1) * 512 + lane * 8];
            bf16x8 bn0 = *(const bf16x8*)&L[3 * 2048 + (wn / 16 + 0) * 512 + lane * 8];
            bf16x8 bn1 = *(const bf16x8*)&L[3 * 2048 + (wn / 16 + 1) * 512 + lane * 8];

            accR[0][0] = __builtin_amdgcn_mfma_f32_16x16x32_bf16(a0, br0, accR[0][0], 0, 0, 0);
            accR[0][1] = __builtin_amdgcn_mfma_f32_16x16x32_bf16(a0, br1, accR[0][1], 0, 0, 0);
            accR[1][0] = __builtin_amdgcn_mfma_f32_16x16x32_bf16(a1, br0, accR[1][0], 0, 0, 0);
            accR[1][1] = __builtin_amdgcn_mfma_f32_16x16x32_bf16(a1, br1, accR[1][1], 0, 0, 0);
            accZ[0][0] = __builtin_amdgcn_mfma_f32_16x16x32_bf16(a0, bz0, accZ[0][0], 0, 0, 0);
            accZ[0][1] = __builtin_amdgcn_mfma_f32_16x16x32_bf16(a0, bz1, accZ[0][1], 0, 0, 0);
            accZ[1][0] = __builtin_amdgcn_mfma_f32_16x16x32_bf16(a1, bz0, accZ[1][0], 0, 0, 0);
            accZ[1][1] = __builtin_amdgcn_mfma_f32_16x16x32_bf16(a1, bz1, accZ[1][1], 0, 0, 0);
            if (half == 0) {
                accNI[0][0] = __builtin_amdgcn_mfma_f32_16x16x32_bf16(a0, bn0, accNI[0][0], 0, 0, 0);
                accNI[0][1] = __builtin_amdgcn_mfma_f32_16x16x32_bf16(a0, bn1, accNI[0][1], 0, 0, 0);
                accNI[1][0] = __builtin_amdgcn_mfma_f32_16x16x32_bf16(a1, bn0, accNI[1][0], 0, 0, 0);
                accNI[1][1] = __builtin_amdgcn_mfma_f32_16x16x32_bf16(a1, bn1, accNI[1][1], 0, 0, 0);
            } else {
                accNH[0][0] = __builtin_amdgcn_mfma_f32_16x16x32_bf16(a0, bn0, accNH[0][0], 0, 0, 0);
                accNH[0][1] = __builtin_amdgcn_mfma_f32_16x16x32_bf16(a0, bn1, accNH[0][1], 0, 0, 0);
                accNH[1][0] = __builtin_amdgcn_mfma_f32_16x16x32_bf16(a1, bn0, accNH[1][0], 0, 0, 0);
                accNH[1][1] = __builtin_amdgcn_mfma_f32_16x16x32_bf16(a1, bn1, accNH[1][1], 0, 0, 0);
            }
        }
    }

    #pragma unroll
    for (int i = 0; i < 2; ++i) {
        #pragma unroll
        for (int reg = 0; reg < 4; ++reg) {
            int row = rowBase + wm + i * 16 + q * 4 + reg;
            if (row >= N) continue;
            #pragma unroll
            for (int j = 0; j < 2; ++j) {
                int col = colBase + wn + j * 16 + r;
                float rg = sigmoidf_(accR[i][j][reg] + bir[col]);
                float zg = sigmoidf_(accZ[i][j][reg] + biz[col]);
                float ng = tanhf(accNI[i][j][reg] + bin[col] + rg * (accNH[i][j][reg] + bhn[col]));
                float h = emb_f32[(size_t)row * H + col];
                out[(size_t)row * H + col] = (1.0f - zg) * ng + zg * h;
            }
        }
    }
}

extern "C" void kernel_launch(void* const* d_in, const int* in_sizes, int n_in,
                              void* d_out, int out_size, void* d_ws, size_t ws_size,
                              hipStream_t stream) {
    const float* emb     = (const float*)d_in[0];
    const int*   src_idx = (const int*)d_in[1];
    const int*   dst_idx = (const int*)d_in[2];
    const int*   etype   = (const int*)d_in[3];
    const float* W_edge  = (const float*)d_in[6];
    const float* b_edge  = (const float*)d_in[7];
    const float* Wir = (const float*)d_in[8];
    const float* Wiz = (const float*)d_in[9];
    const float* Win = (const float*)d_in[10];
    const float* bir = (const float*)d_in[11];
    const float* biz = (const float*)d_in[12];
    const float* bin = (const float*)d_in[13];
    const float* Whr = (const float*)d_in[14];
    const float* Whz = (const float*)d_in[15];
    const float* Whn = (const float*)d_in[16];
    const float* bhn = (const float*)d_in[17];

    const int E = in_sizes[1];
    const int N = in_sizes[0] / H;
    const int NH = N * H;
    const int maxRowTiles = (E + BM - 1) / BM + NT;

    char* ws = (char*)d_ws;
    unsigned short* prop_bf  = (unsigned short*)ws;  ws += (size_t)NH * 2;
    unsigned short* emb_bf   = (unsigned short*)ws;  ws += (size_t)NH * 2;
    unsigned short* msgbuf   = (unsigned short*)ws;  ws += (size_t)E * H * 2;
    unsigned short* Brt      = (unsigned short*)ws;  ws += 512 * 1024 * 2;
    unsigned short* Bzt      = (unsigned short*)ws;  ws += 512 * 1024 * 2;
    unsigned short* Bnit     = (unsigned short*)ws;  ws += 512 * 512 * 2;
    unsigned short* Bnht     = (unsigned short*)ws;  ws += 512 * 512 * 2;
    unsigned short* WeT      = (unsigned short*)ws;  ws += 3072 * 512 * 2;
    int* meta      = (int*)ws;  ws += 32 * 4;
    int* typePerm  = (int*)ws;  ws += (size_t)maxRowTiles * BM * 4;
    int* nodeCnt   = (int*)ws;  ws += (size_t)N * 4;
    int* nodeStart = (int*)ws;  ws += ((size_t)N + 4) * 4;
    int* cursor    = (int*)ws;  ws += (size_t)N * 4;
    int* partials  = (int*)ws;  ws += 64 * 4;
    int* destSlot  = (int*)ws;

    hipMemsetAsync(meta, 0, 32 * 4, stream);
    hipMemsetAsync(typePerm, 0xFF, (size_t)maxRowTiles * BM * 4, stream);
    hipMemsetAsync(nodeCnt, 0, (size_t)N * 4, stream);
    hipMemsetAsync(cursor, 0, (size_t)N * 4, stream);

    const int n4 = NH / 4;
    conv_bf16_kernel<<<(n4 + 255) / 256, 256, 0, stream>>>(emb, emb_bf, n4);
    conv_gru_w_kernel<<<(512 * 1024 + 255) / 256, 256, 0, stream>>>(
        Wir, Wiz, Win, Whr, Whz, Whn, Brt, Bzt, Bnit, Bnht);
    conv_edge_w_kernel<<<(3072 * 512 + 255) / 256, 256, 0, stream>>>(W_edge, WeT);

    // type sort
    hist_kernel<<<(E + 255) / 256, 256, 0, stream>>>(etype, E, meta);
    prefix_kernel<<<1, 64, 0, stream>>>(meta);
    scatter_perm_kernel<<<(E + 255) / 256, 256, 0, stream>>>(etype, E, meta, typePerm);

    // dest sort (slots)
    node_hist_kernel<<<(E + 255) / 256, 256, 0, stream>>>(dst_idx, E, nodeCnt);
    const int nB = (N + 1023) / 1024;
    scan1_kernel<<<nB, 256, 0, stream>>>(nodeCnt, N, nodeStart, partials);
    scan2_kernel<<<1, 64, 0, stream>>>(partials, nB, nodeStart, N);
    scan3_kernel<<<(N + 255) / 256, 256, 0, stream>>>(nodeStart, partials, N);
    slot_kernel<<<(E + 255) / 256, 256, 0, stream>>>(dst_idx, E, nodeStart, cursor, destSlot);

    // edge messages -> dest-sorted bf16 msgbuf
    dim3 egrid(H / BN, maxRowTiles);
    edge_msg_mfma3<<<egrid, 256, 0, stream>>>(emb_bf, src_idx, b_edge, WeT,
                                              meta, typePerm, destSlot, msgbuf);

    // segment reduce -> prop_bf (writes every element; no memset needed)
    segreduce_kernel<<<((size_t)N * 64 + 255) / 256, 256, 0, stream>>>(msgbuf, nodeStart, prop_bf, N);

    // fused GRU
    dim3 ggrid(H / BN, (N + BM - 1) / BM);
    gru_mfma3<<<ggrid, 256, 0, stream>>>(prop_bf, emb_bf, emb, Brt, Bzt, Bnit, Bnht,
                                         bir, biz, bin, bhn, (float*)d_out, N);
}